// Round 1
// baseline (642.437 us; speedup 1.0000x reference)
//
#include <hip/hip_runtime.h>
#include <hip/hip_bf16.h>
#include <math.h>
#include <stdint.h>

#define BB 2
#define SS 2048
#define DD 512
#define HH 8
#define NTOK (BB*SS)      // 4096 tokens
#define NQKV (3*HH*DD)    // 12288
#define BHD  (HH*DD)      // 4096

typedef __attribute__((ext_vector_type(8))) short short8v;
typedef __attribute__((ext_vector_type(4))) short short4v;
typedef __attribute__((ext_vector_type(4))) float floatx4;

__device__ __forceinline__ unsigned short f2bf(float f) {
  unsigned int u = __builtin_bit_cast(unsigned int, f);
  u = (u + 0x7FFFu + ((u >> 16) & 1u)) >> 16;   // RNE
  return (unsigned short)u;
}

__device__ __forceinline__ void async16(const void* g, void* l) {
  __builtin_amdgcn_global_load_lds(
      (const __attribute__((address_space(1))) unsigned int*)g,
      (__attribute__((address_space(3))) unsigned int*)l, 16, 0, 0);
}

// ---------------- prep: q -> bf16 ----------------
__global__ void k_convert_q(const float* __restrict__ q, unsigned short* __restrict__ qbf) {
  int i = (blockIdx.x * 256 + threadIdx.x) * 4;
  const float4 v = *(const float4*)&q[i];
  ushort4 o;
  o.x = f2bf(v.x); o.y = f2bf(v.y); o.z = f2bf(v.z); o.w = f2bf(v.w);
  *(ushort4*)&qbf[i] = o;
}

// ---------------- prep: transpose weights to B^T bf16 ----------------
// z<24: Wq/Wk/Wv head matrices (512x512) -> Wcat rows n = t*4096+h*512+d, cols z
// z>=24: Wo row-slices (512x512) -> Wot (512 x 4096)
__global__ void k_prep_w(const float* __restrict__ Wq, const float* __restrict__ Wk,
                         const float* __restrict__ Wv, const float* __restrict__ Wo,
                         unsigned short* __restrict__ Wcat, unsigned short* __restrict__ Wot) {
  __shared__ float t[32][33];
  const int z = blockIdx.z;
  const float* in; unsigned short* out; int inLD, outLD;
  if (z < 24) {
    int tsel = z / 8, h = z % 8;
    const float* w = (tsel == 0) ? Wq : (tsel == 1) ? Wk : Wv;
    in = w + (size_t)h * DD * DD;
    out = Wcat + ((size_t)tsel * BHD + (size_t)h * DD) * DD;
    inLD = DD; outLD = DD;
  } else {
    int k = z - 24;
    in = Wo + (size_t)k * DD * DD;
    out = Wot + (size_t)k * DD;
    inLD = DD; outLD = BHD;
  }
  const int tx = threadIdx.x, ty = threadIdx.y;
  const int bx = blockIdx.x * 32, by = blockIdx.y * 32;
  for (int kk = 0; kk < 4; ++kk)
    t[ty + 8*kk][tx] = in[(size_t)(by + ty + 8*kk) * inLD + bx + tx];
  __syncthreads();
  for (int kk = 0; kk < 4; ++kk)
    out[(size_t)(bx + ty + 8*kk) * outLD + by + tx] = f2bf(t[tx][ty + 8*kk]);
}

// ---------------- GEMM1: QKV projection + RoPE epilogue ----------------
// C(4096 x 12288) = qbf(4096x512) @ Wcat^T ; per-(t,h) scatter to Qr/Kr (B,H,S,D) and Vt (B,H,D,S)
__global__ __launch_bounds__(256)
void k_qkv(const unsigned short* __restrict__ Abf, const unsigned short* __restrict__ Bt,
           unsigned short* __restrict__ Qr, unsigned short* __restrict__ Kr,
           unsigned short* __restrict__ Vt) {
  __shared__ short As[128*32];
  __shared__ short Bs[128*32];
  const int tid = threadIdx.x;
  const int m0 = blockIdx.x * 128;
  const int n0 = blockIdx.y * 128;
  const int wave = tid >> 6, lane = tid & 63, qd = lane >> 4, c = lane & 15;
  const int wm = (wave >> 1) * 64, wn = (wave & 1) * 64;
  floatx4 acc[4][4] = {};
  const int e0 = tid * 8;
  const int e1 = e0 + 2048;
  for (int k0 = 0; k0 < 512; k0 += 32) {
    __syncthreads();
    async16(&Abf[(size_t)(m0 + (e0 >> 5)) * 512 + k0 + (e0 & 31)], &As[e0]);
    async16(&Abf[(size_t)(m0 + (e1 >> 5)) * 512 + k0 + (e1 & 31)], &As[e1]);
    async16(&Bt [(size_t)(n0 + (e0 >> 5)) * 512 + k0 + (e0 & 31)], &Bs[e0]);
    async16(&Bt [(size_t)(n0 + (e1 >> 5)) * 512 + k0 + (e1 & 31)], &Bs[e1]);
    __syncthreads();
    short8v a[4], bfr[4];
    for (int mt = 0; mt < 4; ++mt) a[mt]   = *(const short8v*)&As[(wm + mt*16 + c)*32 + qd*8];
    for (int nt = 0; nt < 4; ++nt) bfr[nt] = *(const short8v*)&Bs[(wn + nt*16 + c)*32 + qd*8];
    for (int mt = 0; mt < 4; ++mt)
      for (int nt = 0; nt < 4; ++nt)
        acc[mt][nt] = __builtin_amdgcn_mfma_f32_16x16x32_bf16(a[mt], bfr[nt], acc[mt][nt], 0, 0, 0);
  }
  const int tsel = n0 >> 12;
  const int h = (n0 >> 9) & 7;
  const int bat = m0 >> 11;
  const int bh = bat * HH + h;
  const int dloc = (n0 & 511) + wn;
  if (tsel < 2) {
    unsigned short* dst = (tsel == 0) ? Qr : Kr;
    for (int nt = 0; nt < 4; ++nt) {
      const int d = dloc + nt*16 + c;
      const float invf = exp2f(-13.287712379549449f * (1.0f/256.0f) * (float)(d >> 1));
      for (int mt = 0; mt < 4; ++mt) {
        const int mrow = (m0 & 2047) + wm + mt*16 + qd*4;
        for (int r = 0; r < 4; ++r) {
          const int s = mrow + r;
          float v = acc[mt][nt][r];
          float p = __shfl_xor(v, 1, 64);
          float sn, cs;
          __sincosf((float)s * invf, &sn, &cs);
          float res = (d & 1) ? (p * sn + v * cs) : (v * cs - p * sn);
          if (tsel == 0) res *= 0.044194173824159216f;  // 1/sqrt(512), folded into Q
          dst[((size_t)bh * SS + s) * DD + d] = f2bf(res);
        }
      }
    }
  } else {
    for (int nt = 0; nt < 4; ++nt) {
      const int d = dloc + nt*16 + c;
      const size_t vbase = ((size_t)bh * DD + d) * SS;
      for (int mt = 0; mt < 4; ++mt) {
        const int s = (m0 & 2047) + wm + mt*16 + qd*4;
        ushort4 u;
        u.x = f2bf(acc[mt][nt][0]); u.y = f2bf(acc[mt][nt][1]);
        u.z = f2bf(acc[mt][nt][2]); u.w = f2bf(acc[mt][nt][3]);
        *(ushort4*)&Vt[vbase + s] = u;
      }
    }
  }
}

// ---------------- pass A: softmax denominators l_z (no max needed, |S|~O(1)) ----------------
__global__ __launch_bounds__(256)
void k_lsum(const unsigned short* __restrict__ Qr, const unsigned short* __restrict__ Kr,
            float* __restrict__ rl) {
  __shared__ short Qs[64*32];
  __shared__ short Ks[128*32];
  __shared__ float part[2][64];
  const int tid = threadIdx.x;
  const int bh = blockIdx.y;
  const int wave = tid >> 6, lane = tid & 63, qd = lane >> 4, c = lane & 15;
  const int zw = (wave >> 1) * 32, sw = (wave & 1) * 64;
  const size_t qb = (size_t)bh * SS * DD;
  for (int rep = 0; rep < 2; ++rep) {
    const int zb = rep ? (31 - (int)blockIdx.x) : (int)blockIdx.x;  // balance pairing
    const int z0 = zb * 64;
    float rs[2][4] = {};
    const int tmax = (z0 + 63) >> 7;
    for (int ts = 0; ts <= tmax; ++ts) {
      const int s0 = ts * 128;
      floatx4 sacc[2][4] = {};
      for (int k0 = 0; k0 < 512; k0 += 32) {
        __syncthreads();
        { const int e = tid * 8;
          async16(&Qr[qb + (size_t)(z0 + (e >> 5)) * 512 + k0 + (e & 31)], &Qs[e]);
          async16(&Kr[qb + (size_t)(s0 + (e >> 5)) * 512 + k0 + (e & 31)], &Ks[e]);
          const int e2 = e + 2048;
          async16(&Kr[qb + (size_t)(s0 + (e2 >> 5)) * 512 + k0 + (e2 & 31)], &Ks[e2]);
        }
        __syncthreads();
        short8v a[2], bfr[4];
        for (int tz = 0; tz < 2; ++tz) a[tz]   = *(const short8v*)&Qs[(zw + tz*16 + c)*32 + qd*8];
        for (int st = 0; st < 4; ++st) bfr[st] = *(const short8v*)&Ks[(sw + st*16 + c)*32 + qd*8];
        for (int tz = 0; tz < 2; ++tz)
          for (int st = 0; st < 4; ++st)
            sacc[tz][st] = __builtin_amdgcn_mfma_f32_16x16x32_bf16(a[tz], bfr[st], sacc[tz][st], 0, 0, 0);
      }
      for (int tz = 0; tz < 2; ++tz) {
        const int zg = z0 + zw + tz*16 + qd*4;
        for (int st = 0; st < 4; ++st) {
          const int sg = s0 + sw + st*16 + c;
          for (int r = 0; r < 4; ++r)
            rs[tz][r] += (sg <= zg + r) ? __expf(sacc[tz][st][r]) : 0.0f;
        }
      }
    }
    for (int off = 1; off < 16; off <<= 1)
      for (int tz = 0; tz < 2; ++tz)
        for (int r = 0; r < 4; ++r)
          rs[tz][r] += __shfl_xor(rs[tz][r], off, 64);
    __syncthreads();
    if (c == 0)
      for (int tz = 0; tz < 2; ++tz)
        for (int r = 0; r < 4; ++r)
          part[wave & 1][zw + tz*16 + qd*4 + r] = rs[tz][r];
    __syncthreads();
    if (tid < 64) rl[(size_t)bh * SS + z0 + tid] = 1.0f / (part[0][tid] + part[1][tid]);
  }
}

// ---------------- pass B: out^T(d,s) += V^T(d,z) @ P(z,s), P via LDS ----------------
__global__ __launch_bounds__(512)
void k_attn(const unsigned short* __restrict__ Qr, const unsigned short* __restrict__ Kr,
            const unsigned short* __restrict__ Vt, const float* __restrict__ rl,
            unsigned short* __restrict__ Ocat) {
  __shared__ short Qs[128*32];
  __shared__ short Ks[64*32];
  __shared__ unsigned short Pl[64*132];   // [s][z], stride 132 (16B-align + bank spread)
  __shared__ float lls[128];
  const int tid = threadIdx.x;
  const int bh = blockIdx.y;
  const int bat = bh >> 3, h = bh & 7;
  const int wave = tid >> 6, lane = tid & 63, qd = lane >> 4, c = lane & 15;
  const int dw = wave * 64;                       // phase-2: wave owns d-range
  const int zw = (wave >> 1) * 32, sw = (wave & 1) * 32;  // phase-1 roles
  const size_t qb = (size_t)bh * SS * DD;
  const size_t vbb = (size_t)bh * DD * SS;
  for (int rep = 0; rep < 2; ++rep) {
    const int sbi = rep ? (31 - (int)blockIdx.x) : (int)blockIdx.x;  // balance pairing
    const int s0 = sbi * 64;
    floatx4 acc[4][4] = {};   // [st][dt] : out^T tile (64 d per wave) x (64 s)
    for (int zt = s0 & ~127; zt < SS; zt += 128) {
      if (tid < 128) lls[tid] = rl[(size_t)bh * SS + zt + tid];
      // ---- phase 1: scores S_t (z 128 x s 64) ----
      floatx4 sacc[2][2] = {};
      for (int k0 = 0; k0 < 512; k0 += 32) {
        __syncthreads();
        { const int e = tid * 8;
          async16(&Qr[qb + (size_t)(zt + (e >> 5)) * 512 + k0 + (e & 31)], &Qs[e]);
          if (tid < 256)
            async16(&Kr[qb + (size_t)(s0 + (e >> 5)) * 512 + k0 + (e & 31)], &Ks[e]);
        }
        __syncthreads();
        short8v a[2], bfr[2];
        for (int tz = 0; tz < 2; ++tz) a[tz]   = *(const short8v*)&Qs[(zw + tz*16 + c)*32 + qd*8];
        for (int st = 0; st < 2; ++st) bfr[st] = *(const short8v*)&Ks[(sw + st*16 + c)*32 + qd*8];
        for (int tz = 0; tz < 2; ++tz)
          for (int st = 0; st < 2; ++st)
            sacc[tz][st] = __builtin_amdgcn_mfma_f32_16x16x32_bf16(a[tz], bfr[st], sacc[tz][st], 0, 0, 0);
      }
      // ---- exp, * rcp_l, causal mask, P^T -> LDS ----
      for (int tz = 0; tz < 2; ++tz) {
        const int zl = zw + tz*16 + qd*4;
        const int zg = zt + zl;
        for (int st = 0; st < 2; ++st) {
          const int sl = sw + st*16 + c;
          const int sg = s0 + sl;
          ushort4 u;
          float p0 = (sg <= zg + 0) ? __expf(sacc[tz][st][0]) * lls[zl + 0] : 0.0f;
          float p1 = (sg <= zg + 1) ? __expf(sacc[tz][st][1]) * lls[zl + 1] : 0.0f;
          float p2 = (sg <= zg + 2) ? __expf(sacc[tz][st][2]) * lls[zl + 2] : 0.0f;
          float p3 = (sg <= zg + 3) ? __expf(sacc[tz][st][3]) * lls[zl + 3] : 0.0f;
          u.x = f2bf(p0); u.y = f2bf(p1); u.z = f2bf(p2); u.w = f2bf(p3);
          *(ushort4*)&Pl[sl * 132 + zl] = u;
        }
      }
      __syncthreads();
      // ---- phase 2: acc += V^T @ P  (K=16 MFMA; P's D-layout == B-operand layout) ----
      for (int kc = 0; kc < 8; ++kc) {
        const int zo = kc * 16 + qd * 4;
        short4v av[4], bp[4];
        for (int dt = 0; dt < 4; ++dt)
          av[dt] = *(const short4v*)&Vt[vbb + (size_t)(dw + dt*16 + c) * SS + zt + zo];
        for (int st = 0; st < 4; ++st)
          bp[st] = *(const short4v*)&Pl[(st*16 + c) * 132 + zo];
        for (int st = 0; st < 4; ++st)
          for (int dt = 0; dt < 4; ++dt)
            acc[st][dt] = __builtin_amdgcn_mfma_f32_16x16x16bf16_1k(av[dt], bp[st], acc[st][dt], 0, 0, 0);
      }
      // next z-tile's first __syncthreads protects Pl/Qs/Ks/lls
    }
    // ---- epilogue: out^T -> Ocat[token][h*512 + d] (bf16) ----
    for (int st = 0; st < 4; ++st) {
      const int sg = s0 + st*16 + c;
      const size_t ob = ((size_t)(bat * SS + sg)) * BHD + (size_t)h * DD;
      for (int dt = 0; dt < 4; ++dt) {
        const int d = dw + dt*16 + qd*4;
        ushort4 u;
        u.x = f2bf(acc[st][dt][0]); u.y = f2bf(acc[st][dt][1]);
        u.z = f2bf(acc[st][dt][2]); u.w = f2bf(acc[st][dt][3]);
        *(ushort4*)&Ocat[ob + d] = u;
      }
    }
    __syncthreads();
  }
}

// ---------------- GEMM4: out = Ocat(4096x4096) @ Wo ; fp32 output ----------------
__global__ __launch_bounds__(256)
void k_oproj(const unsigned short* __restrict__ Ocat, const unsigned short* __restrict__ Wot,
             float* __restrict__ out) {
  __shared__ short As[64*32];
  __shared__ short Bs[128*32];
  const int tid = threadIdx.x;
  const int m0 = blockIdx.x * 64;
  const int n0 = blockIdx.y * 128;
  const int wave = tid >> 6, lane = tid & 63, qd = lane >> 4, c = lane & 15;
  const int wm = (wave >> 1) * 32, wn = (wave & 1) * 64;
  floatx4 acc[2][4] = {};
  const int e0 = tid * 8;
  const int e1 = e0 + 2048;
  for (int k0 = 0; k0 < BHD; k0 += 32) {
    __syncthreads();
    async16(&Ocat[(size_t)(m0 + (e0 >> 5)) * BHD + k0 + (e0 & 31)], &As[e0]);
    async16(&Wot [(size_t)(n0 + (e0 >> 5)) * BHD + k0 + (e0 & 31)], &Bs[e0]);
    async16(&Wot [(size_t)(n0 + (e1 >> 5)) * BHD + k0 + (e1 & 31)], &Bs[e1]);
    __syncthreads();
    short8v a[2], bfr[4];
    for (int mt = 0; mt < 2; ++mt) a[mt]   = *(const short8v*)&As[(wm + mt*16 + c)*32 + qd*8];
    for (int nt = 0; nt < 4; ++nt) bfr[nt] = *(const short8v*)&Bs[(wn + nt*16 + c)*32 + qd*8];
    for (int mt = 0; mt < 2; ++mt)
      for (int nt = 0; nt < 4; ++nt)
        acc[mt][nt] = __builtin_amdgcn_mfma_f32_16x16x32_bf16(a[mt], bfr[nt], acc[mt][nt], 0, 0, 0);
  }
  for (int mt = 0; mt < 2; ++mt) {
    const int m = m0 + wm + mt*16 + qd*4;
    for (int nt = 0; nt < 4; ++nt) {
      const int n = n0 + wn + nt*16 + c;
      for (int r = 0; r < 4; ++r)
        out[(size_t)(m + r) * DD + n] = acc[mt][nt][r];
    }
  }
}

extern "C" void kernel_launch(void* const* d_in, const int* in_sizes, int n_in,
                              void* d_out, int out_size, void* d_ws, size_t ws_size,
                              hipStream_t stream) {
  const float* q  = (const float*)d_in[0];
  const float* Wq = (const float*)d_in[1];
  const float* Wk = (const float*)d_in[2];
  const float* Wv = (const float*)d_in[3];
  const float* Wo = (const float*)d_in[4];

  char* p = (char*)d_ws;
  auto alloc = [&](size_t bytes) { char* r = p; p += (bytes + 255) & ~(size_t)255; return r; };
  unsigned short* qbf  = (unsigned short*)alloc((size_t)NTOK * DD * 2);        //   4 MB
  unsigned short* Wcat = (unsigned short*)alloc((size_t)NQKV * DD * 2);        //  12.6 MB
  unsigned short* Wot  = (unsigned short*)alloc((size_t)DD * BHD * 2);         //   4.2 MB
  unsigned short* Qr   = (unsigned short*)alloc((size_t)BB*HH*SS*DD * 2);      //  33.5 MB
  unsigned short* Kr   = (unsigned short*)alloc((size_t)BB*HH*SS*DD * 2);      //  33.5 MB
  unsigned short* Vt   = (unsigned short*)alloc((size_t)BB*HH*SS*DD * 2);      //  33.5 MB
  unsigned short* Ocat = (unsigned short*)alloc((size_t)NTOK * BHD * 2);       //  33.5 MB
  float*          rl   = (float*)alloc((size_t)BB*HH*SS * 4);                  //  0.13 MB

  k_convert_q<<<NTOK*DD/1024, 256, 0, stream>>>(q, qbf);
  k_prep_w<<<dim3(16,16,32), dim3(32,8), 0, stream>>>(Wq, Wk, Wv, Wo, Wcat, Wot);
  k_qkv<<<dim3(32,96), 256, 0, stream>>>(qbf, Wcat, Qr, Kr, Vt);
  k_lsum<<<dim3(16,16), 256, 0, stream>>>(Qr, Kr, rl);
  k_attn<<<dim3(16,16), 512, 0, stream>>>(Qr, Kr, Vt, rl, Ocat);
  k_oproj<<<dim3(64,4), 256, 0, stream>>>(Ocat, Wot, (float*)d_out);
}

// Round 2
// 425.743 us; speedup vs baseline: 1.5090x; 1.5090x over previous
//
#include <hip/hip_runtime.h>
#include <hip/hip_bf16.h>
#include <math.h>
#include <stdint.h>

#define BB 2
#define SS 2048
#define DD 512
#define HH 8
#define NTOK (BB*SS)      // 4096 tokens
#define NQKV (3*HH*DD)    // 12288
#define BHD  (HH*DD)      // 4096
#define NBH  (BB*HH)      // 16
#define NTILE 136         // tri(16): causal 128x128 tiles per (b,h)

typedef __attribute__((ext_vector_type(8))) short short8v;
typedef __attribute__((ext_vector_type(4))) float floatx4;

__device__ __forceinline__ unsigned short f2bf(float f) {
  unsigned int u = __builtin_bit_cast(unsigned int, f);
  u = (u + 0x7FFFu + ((u >> 16) & 1u)) >> 16;   // RNE
  return (unsigned short)u;
}
__device__ __forceinline__ float bf2f(unsigned short s) {
  unsigned int u = ((unsigned int)s) << 16;
  return __builtin_bit_cast(float, u);
}
__device__ __forceinline__ void async16(const void* g, void* l) {
  __builtin_amdgcn_global_load_lds(
      (const __attribute__((address_space(1))) unsigned int*)g,
      (__attribute__((address_space(3))) unsigned int*)l, 16, 0, 0);
}

// ---------------- prep: q -> bf16 ----------------
__global__ void k_convert_q(const float* __restrict__ q, unsigned short* __restrict__ qbf) {
  int i = (blockIdx.x * 256 + threadIdx.x) * 4;
  const float4 v = *(const float4*)&q[i];
  ushort4 o;
  o.x = f2bf(v.x); o.y = f2bf(v.y); o.z = f2bf(v.z); o.w = f2bf(v.w);
  *(ushort4*)&qbf[i] = o;
}

// ---------------- prep: transpose weights to B^T bf16 ----------------
__global__ void k_prep_w(const float* __restrict__ Wq, const float* __restrict__ Wk,
                         const float* __restrict__ Wv, const float* __restrict__ Wo,
                         unsigned short* __restrict__ Wcat, unsigned short* __restrict__ Wot) {
  __shared__ float t[32][33];
  const int z = blockIdx.z;
  const float* in; unsigned short* out; int inLD, outLD;
  if (z < 24) {
    int tsel = z / 8, h = z % 8;
    const float* w = (tsel == 0) ? Wq : (tsel == 1) ? Wk : Wv;
    in = w + (size_t)h * DD * DD;
    out = Wcat + ((size_t)tsel * BHD + (size_t)h * DD) * DD;
    inLD = DD; outLD = DD;
  } else {
    int k = z - 24;
    in = Wo + (size_t)k * DD * DD;
    out = Wot + (size_t)k * DD;
    inLD = DD; outLD = BHD;
  }
  const int tx = threadIdx.x, ty = threadIdx.y;
  const int bx = blockIdx.x * 32, by = blockIdx.y * 32;
  for (int kk = 0; kk < 4; ++kk)
    t[ty + 8*kk][tx] = in[(size_t)(by + ty + 8*kk) * inLD + bx + tx];
  __syncthreads();
  for (int kk = 0; kk < 4; ++kk)
    out[(size_t)(bx + ty + 8*kk) * outLD + by + tx] = f2bf(t[tx][ty + 8*kk]);
}

// ---------------- GEMM1: QKV projection + RoPE epilogue ----------------
__global__ __launch_bounds__(256)
void k_qkv(const unsigned short* __restrict__ Abf, const unsigned short* __restrict__ Bt,
           unsigned short* __restrict__ Qr, unsigned short* __restrict__ Kr,
           unsigned short* __restrict__ Vt) {
  __shared__ short As[128*32];
  __shared__ short Bs[128*32];
  const int tid = threadIdx.x;
  const int m0 = blockIdx.x * 128;
  const int n0 = blockIdx.y * 128;
  const int wave = tid >> 6, lane = tid & 63, qd = lane >> 4, c = lane & 15;
  const int wm = (wave >> 1) * 64, wn = (wave & 1) * 64;
  floatx4 acc[4][4] = {};
  const int e0 = tid * 8;
  const int e1 = e0 + 2048;
  for (int k0 = 0; k0 < 512; k0 += 32) {
    __syncthreads();
    async16(&Abf[(size_t)(m0 + (e0 >> 5)) * 512 + k0 + (e0 & 31)], &As[e0]);
    async16(&Abf[(size_t)(m0 + (e1 >> 5)) * 512 + k0 + (e1 & 31)], &As[e1]);
    async16(&Bt [(size_t)(n0 + (e0 >> 5)) * 512 + k0 + (e0 & 31)], &Bs[e0]);
    async16(&Bt [(size_t)(n0 + (e1 >> 5)) * 512 + k0 + (e1 & 31)], &Bs[e1]);
    __syncthreads();
    short8v a[4], bfr[4];
    for (int mt = 0; mt < 4; ++mt) a[mt]   = *(const short8v*)&As[(wm + mt*16 + c)*32 + qd*8];
    for (int nt = 0; nt < 4; ++nt) bfr[nt] = *(const short8v*)&Bs[(wn + nt*16 + c)*32 + qd*8];
    for (int mt = 0; mt < 4; ++mt)
      for (int nt = 0; nt < 4; ++nt)
        acc[mt][nt] = __builtin_amdgcn_mfma_f32_16x16x32_bf16(a[mt], bfr[nt], acc[mt][nt], 0, 0, 0);
  }
  const int tsel = n0 >> 12;
  const int h = (n0 >> 9) & 7;
  const int bat = m0 >> 11;
  const int bh = bat * HH + h;
  const int dloc = (n0 & 511) + wn;
  if (tsel < 2) {
    unsigned short* dst = (tsel == 0) ? Qr : Kr;
    for (int nt = 0; nt < 4; ++nt) {
      const int d = dloc + nt*16 + c;
      const float invf = exp2f(-13.287712379549449f * (1.0f/256.0f) * (float)(d >> 1));
      for (int mt = 0; mt < 4; ++mt) {
        const int mrow = (m0 & 2047) + wm + mt*16 + qd*4;
        for (int r = 0; r < 4; ++r) {
          const int s = mrow + r;
          float v = acc[mt][nt][r];
          float p = __shfl_xor(v, 1, 64);
          float sn, cs;
          __sincosf((float)s * invf, &sn, &cs);
          float res = (d & 1) ? (p * sn + v * cs) : (v * cs - p * sn);
          if (tsel == 0) res *= 0.044194173824159216f;  // 1/sqrt(512) folded into Q
          dst[((size_t)bh * SS + s) * DD + d] = f2bf(res);
        }
      }
    }
  } else {
    for (int nt = 0; nt < 4; ++nt) {
      const int d = dloc + nt*16 + c;
      const size_t vbase = ((size_t)bh * DD + d) * SS;
      for (int mt = 0; mt < 4; ++mt) {
        const int s = (m0 & 2047) + wm + mt*16 + qd*4;
        ushort4 u;
        u.x = f2bf(acc[mt][nt][0]); u.y = f2bf(acc[mt][nt][1]);
        u.z = f2bf(acc[mt][nt][2]); u.w = f2bf(acc[mt][nt][3]);
        *(ushort4*)&Vt[vbase + s] = u;
      }
    }
  }
}

// ---------------- pass A: E = exp(S) panels (bf16, causal triangle) + row sums l_z ----------------
// grid.x = 136 tiles (zb,st), grid.y = bh. Pure 128x128x512 GEMM + epilogue.
__global__ __launch_bounds__(256)
void k_scores(const unsigned short* __restrict__ Qr, const unsigned short* __restrict__ Kr,
              unsigned short* __restrict__ Eg, float* __restrict__ lsum) {
  __shared__ short UN[17408];   // union: As(4096)+Bs(4096) | ET 128x136
  short* As = UN;
  short* Bs = UN + 4096;
  unsigned short* ET = (unsigned short*)UN;
  const int tid = threadIdx.x;
  const int bh = blockIdx.y;
  const int t = blockIdx.x;
  int zb = 0;
  while (((zb + 1) * (zb + 2)) / 2 <= t) ++zb;
  const int st = t - (zb * (zb + 1)) / 2;
  const int z0 = zb * 128, s0 = st * 128;
  const int wave = tid >> 6, lane = tid & 63, qd = lane >> 4, c = lane & 15;
  const int wm = (wave >> 1) * 64, wn = (wave & 1) * 64;
  const size_t qb = (size_t)bh * SS * DD;
  floatx4 acc[4][4] = {};
  const int e0 = tid * 8, e1 = e0 + 2048;
  for (int k0 = 0; k0 < 512; k0 += 32) {
    __syncthreads();
    async16(&Qr[qb + (size_t)(z0 + (e0 >> 5)) * 512 + k0 + (e0 & 31)], &As[e0]);
    async16(&Qr[qb + (size_t)(z0 + (e1 >> 5)) * 512 + k0 + (e1 & 31)], &As[e1]);
    async16(&Kr[qb + (size_t)(s0 + (e0 >> 5)) * 512 + k0 + (e0 & 31)], &Bs[e0]);
    async16(&Kr[qb + (size_t)(s0 + (e1 >> 5)) * 512 + k0 + (e1 & 31)], &Bs[e1]);
    __syncthreads();
    short8v a[4], bfr[4];
    for (int mt = 0; mt < 4; ++mt) a[mt]   = *(const short8v*)&As[(wm + mt*16 + c)*32 + qd*8];
    for (int nt = 0; nt < 4; ++nt) bfr[nt] = *(const short8v*)&Bs[(wn + nt*16 + c)*32 + qd*8];
    for (int mt = 0; mt < 4; ++mt)
      for (int nt = 0; nt < 4; ++nt)
        acc[mt][nt] = __builtin_amdgcn_mfma_f32_16x16x32_bf16(a[mt], bfr[nt], acc[mt][nt], 0, 0, 0);
  }
  // exp (no max: |scores| small), causal mask on diagonal tile, row sums
  const bool diag = (st == zb);
  for (int mt = 0; mt < 4; ++mt) {
    const int zl = wm + mt*16 + qd*4;
    float rs[4] = {0.f, 0.f, 0.f, 0.f};
    for (int nt = 0; nt < 4; ++nt) {
      const int sl = wn + nt*16 + c;
      for (int r = 0; r < 4; ++r) {
        float ev = __expf(acc[mt][nt][r]);
        if (diag && (sl > zl + r)) ev = 0.f;
        acc[mt][nt][r] = ev;
        rs[r] += ev;
      }
    }
    for (int off = 1; off < 16; off <<= 1)
      for (int r = 0; r < 4; ++r) rs[r] += __shfl_xor(rs[r], off, 64);
    if (c == 0)
      for (int r = 0; r < 4; ++r)
        atomicAdd(&lsum[(size_t)bh * SS + z0 + zl + r], rs[r]);
  }
  // transpose to E^T[s][z] via LDS, then coalesced global write
  __syncthreads();
  for (int mt = 0; mt < 4; ++mt) {
    const int zl = wm + mt*16 + qd*4;
    for (int nt = 0; nt < 4; ++nt) {
      const int sl = wn + nt*16 + c;
      ushort4 u;
      u.x = f2bf(acc[mt][nt][0]); u.y = f2bf(acc[mt][nt][1]);
      u.z = f2bf(acc[mt][nt][2]); u.w = f2bf(acc[mt][nt][3]);
      *(ushort4*)&ET[sl * 136 + zl] = u;
    }
  }
  __syncthreads();
  const size_t tb = ((size_t)bh * NTILE + t) * 16384;
  for (int it = 0; it < 8; ++it) {
    const int e = it * 2048 + tid * 8;
    const int row = e >> 7, col = e & 127;
    *(short8v*)&Eg[tb + row * 128 + col] = *(const short8v*)&ET[row * 136 + col];
  }
}

// ---------------- scale V by 1/l_z in place: Vs[d][z] = V^T[d][z] / l[z] ----------------
__global__ void k_vscale(unsigned short* __restrict__ Vt, const float* __restrict__ lsum) {
  const int idx = (blockIdx.x * 256 + threadIdx.x) * 8;
  const int z = idx & (SS - 1);
  const int bh = idx >> 20;   // / (512*2048)
  short8v v = *(const short8v*)&Vt[idx];
  const float* lp = &lsum[(size_t)bh * SS + z];
  short8v o;
  for (int i = 0; i < 8; ++i)
    o[i] = (short)f2bf(bf2f((unsigned short)v[i]) / lp[i]);
  *(short8v*)&Vt[idx] = o;
}

// ---------------- pass B: out^T(128d x 64s) = sum_z Vs^T(d,z) E^T(s,z) — pure GEMM ----------------
__global__ __launch_bounds__(256)
void k_pv(const unsigned short* __restrict__ Eg, const unsigned short* __restrict__ Vs,
          unsigned short* __restrict__ Ocat) {
  __shared__ short Vl[2][128*32];
  __shared__ short El[2][64*32];
  const int tid = threadIdx.x;
  const int d0 = blockIdx.x * 128;
  const int s0 = blockIdx.y * 64;
  const int bh = blockIdx.z;
  const int st = s0 >> 7, sl0 = s0 & 127;
  const int bat = bh >> 3, h = bh & 7;
  const int wave = tid >> 6, lane = tid & 63, qd = lane >> 4, c = lane & 15;
  const int wm = (wave >> 1) * 64, wn = (wave & 1) * 32;
  const size_t vbb = (size_t)bh * DD * SS;
  floatx4 acc[4][2] = {};
  const int e = tid * 8;
  for (int zb = st; zb < 16; ++zb) {
    const size_t tb = ((size_t)bh * NTILE + (zb * (zb + 1)) / 2 + st) * 16384;
    for (int half = 0; half < 2; ++half) {
      const int zbase = zb * 128 + half * 64;
      __syncthreads();
      for (int i = 0; i < 4; ++i) {
        const int ee = e + i * 2048;
        const int kc = ee >> 12, row = (ee >> 5) & 127, col = ee & 31;
        async16(&Vs[vbb + (size_t)(d0 + row) * SS + zbase + kc * 32 + col], &Vl[kc][row * 32 + col]);
      }
      for (int i = 0; i < 2; ++i) {
        const int ee = e + i * 2048;
        const int kc = ee >> 11, row = (ee >> 5) & 63, col = ee & 31;
        async16(&Eg[tb + (size_t)(sl0 + row) * 128 + half * 64 + kc * 32 + col], &El[kc][row * 32 + col]);
      }
      __syncthreads();
      for (int kc = 0; kc < 2; ++kc) {
        short8v a[4], b[2];
        for (int dt = 0; dt < 4; ++dt) a[dt] = *(const short8v*)&Vl[kc][(wm + dt*16 + c)*32 + qd*8];
        for (int nt = 0; nt < 2; ++nt) b[nt] = *(const short8v*)&El[kc][(wn + nt*16 + c)*32 + qd*8];
        for (int dt = 0; dt < 4; ++dt)
          for (int nt = 0; nt < 2; ++nt)
            acc[dt][nt] = __builtin_amdgcn_mfma_f32_16x16x32_bf16(a[dt], b[nt], acc[dt][nt], 0, 0, 0);
      }
    }
  }
  for (int nt = 0; nt < 2; ++nt) {
    const int sg = s0 + wn + nt*16 + c;
    const size_t ob = ((size_t)(bat * SS + sg)) * BHD + (size_t)h * DD + d0;
    for (int dt = 0; dt < 4; ++dt) {
      const int dloc = wm + dt*16 + qd*4;
      ushort4 u;
      u.x = f2bf(acc[dt][nt][0]); u.y = f2bf(acc[dt][nt][1]);
      u.z = f2bf(acc[dt][nt][2]); u.w = f2bf(acc[dt][nt][3]);
      *(ushort4*)&Ocat[ob + dloc] = u;
    }
  }
}

// ---------------- GEMM4: out += Ocat @ Wo, split-K=2, f32 atomics into zeroed d_out ----------------
__global__ __launch_bounds__(256)
void k_oproj(const unsigned short* __restrict__ Ocat, const unsigned short* __restrict__ Wot,
             float* __restrict__ out) {
  __shared__ short As[64*32];
  __shared__ short Bs[64*32];
  const int tid = threadIdx.x;
  const int m0 = blockIdx.x * 64;
  const int n0 = blockIdx.y * 64;
  const int ks = blockIdx.z * 2048;
  const int wave = tid >> 6, lane = tid & 63, qd = lane >> 4, c = lane & 15;
  const int wm = (wave >> 1) * 32, wn = (wave & 1) * 32;
  floatx4 acc[2][2] = {};
  const int e = tid * 8;
  for (int k0 = ks; k0 < ks + 2048; k0 += 32) {
    __syncthreads();
    async16(&Ocat[(size_t)(m0 + (e >> 5)) * BHD + k0 + (e & 31)], &As[e]);
    async16(&Wot [(size_t)(n0 + (e >> 5)) * BHD + k0 + (e & 31)], &Bs[e]);
    __syncthreads();
    short8v a[2], b[2];
    for (int mt = 0; mt < 2; ++mt) a[mt] = *(const short8v*)&As[(wm + mt*16 + c)*32 + qd*8];
    for (int nt = 0; nt < 2; ++nt) b[nt] = *(const short8v*)&Bs[(wn + nt*16 + c)*32 + qd*8];
    for (int mt = 0; mt < 2; ++mt)
      for (int nt = 0; nt < 2; ++nt)
        acc[mt][nt] = __builtin_amdgcn_mfma_f32_16x16x32_bf16(a[mt], b[nt], acc[mt][nt], 0, 0, 0);
  }
  for (int mt = 0; mt < 2; ++mt) {
    const int m = m0 + wm + mt*16 + qd*4;
    for (int nt = 0; nt < 2; ++nt) {
      const int n = n0 + wn + nt*16 + c;
      for (int r = 0; r < 4; ++r)
        atomicAdd(&out[(size_t)(m + r) * DD + n], acc[mt][nt][r]);
    }
  }
}

extern "C" void kernel_launch(void* const* d_in, const int* in_sizes, int n_in,
                              void* d_out, int out_size, void* d_ws, size_t ws_size,
                              hipStream_t stream) {
  const float* q  = (const float*)d_in[0];
  const float* Wq = (const float*)d_in[1];
  const float* Wk = (const float*)d_in[2];
  const float* Wv = (const float*)d_in[3];
  const float* Wo = (const float*)d_in[4];

  // workspace layout with lifetime-based aliasing (peak ~176 MB):
  //  [0 .. 71.3MB)   Eg   (written in k_scores; overlays qbf+Wcat which die after k_qkv)
  //  [71.3 .. 75.5)  Wot
  //  [75.5 .. 109)   Qr   (dies after k_scores; Ocat overlays it)
  //  [109 .. 142.6)  Kr
  //  [142.6 ..176.2) Vt   (scaled in place by k_vscale)
  //  [176.2 .. )     lsum
  char* base = (char*)d_ws;
  unsigned short* Eg   = (unsigned short*)base;                       // 71,303,168 B
  unsigned short* qbf  = (unsigned short*)base;                       //  4,194,304 B (overlay)
  unsigned short* Wcat = (unsigned short*)(base + 4194304);           // 12,582,912 B (overlay)
  char* p = base + 71303168;
  unsigned short* Wot  = (unsigned short*)p; p += 4194304;
  unsigned short* Qr   = (unsigned short*)p;
  unsigned short* Ocat = (unsigned short*)p; p += 33554432;
  unsigned short* Kr   = (unsigned short*)p; p += 33554432;
  unsigned short* Vt   = (unsigned short*)p; p += 33554432;
  float*          lsum = (float*)p;

  hipMemsetAsync(lsum, 0, (size_t)NBH * SS * 4, stream);
  hipMemsetAsync(d_out, 0, (size_t)NTOK * DD * 4, stream);

  k_convert_q<<<NTOK*DD/1024, 256, 0, stream>>>(q, qbf);
  k_prep_w<<<dim3(16,16,32), dim3(32,8), 0, stream>>>(Wq, Wk, Wv, Wo, Wcat, Wot);
  k_qkv<<<dim3(32,96), 256, 0, stream>>>(qbf, Wcat, Qr, Kr, Vt);
  k_scores<<<dim3(NTILE,16), 256, 0, stream>>>(Qr, Kr, Eg, lsum);
  k_vscale<<<NBH*DD*SS/(256*8), 256, 0, stream>>>(Vt, lsum);
  k_pv<<<dim3(4,32,16), 256, 0, stream>>>(Eg, Vt, Ocat);
  k_oproj<<<dim3(64,8,2), 256, 0, stream>>>(Ocat, Wot, (float*)d_out);
}

// Round 3
// 424.607 us; speedup vs baseline: 1.5130x; 1.0027x over previous
//
#include <hip/hip_runtime.h>
#include <hip/hip_bf16.h>
#include <math.h>
#include <stdint.h>

#define BB 2
#define SS 2048
#define DD 512
#define HH 8
#define NTOK (BB*SS)      // 4096 tokens
#define NQKV (3*HH*DD)    // 12288
#define BHD  (HH*DD)      // 4096
#define NBH  (BB*HH)      // 16
#define NTILE 136         // tri(16): causal 128x128 tiles per (b,h)

typedef __attribute__((ext_vector_type(8))) short short8v;
typedef __attribute__((ext_vector_type(4))) float floatx4;

__device__ __forceinline__ unsigned short f2bf(float f) {
  unsigned int u = __builtin_bit_cast(unsigned int, f);
  u = (u + 0x7FFFu + ((u >> 16) & 1u)) >> 16;   // RNE
  return (unsigned short)u;
}
__device__ __forceinline__ float bf2f(unsigned short s) {
  unsigned int u = ((unsigned int)s) << 16;
  return __builtin_bit_cast(float, u);
}
__device__ __forceinline__ void async16(const void* g, void* l) {
  __builtin_amdgcn_global_load_lds(
      (const __attribute__((address_space(1))) unsigned int*)g,
      (__attribute__((address_space(3))) unsigned int*)l, 16, 0, 0);
}

// ---------------- prep: q -> bf16 ----------------
__global__ void k_convert_q(const float* __restrict__ q, unsigned short* __restrict__ qbf) {
  int i = (blockIdx.x * 256 + threadIdx.x) * 4;
  const float4 v = *(const float4*)&q[i];
  ushort4 o;
  o.x = f2bf(v.x); o.y = f2bf(v.y); o.z = f2bf(v.z); o.w = f2bf(v.w);
  *(ushort4*)&qbf[i] = o;
}

// ---------------- prep: transpose weights to B^T bf16 ----------------
__global__ void k_prep_w(const float* __restrict__ Wq, const float* __restrict__ Wk,
                         const float* __restrict__ Wv, const float* __restrict__ Wo,
                         unsigned short* __restrict__ Wcat, unsigned short* __restrict__ Wot) {
  __shared__ float t[32][33];
  const int z = blockIdx.z;
  const float* in; unsigned short* out; int inLD, outLD;
  if (z < 24) {
    int tsel = z / 8, h = z % 8;
    const float* w = (tsel == 0) ? Wq : (tsel == 1) ? Wk : Wv;
    in = w + (size_t)h * DD * DD;
    out = Wcat + ((size_t)tsel * BHD + (size_t)h * DD) * DD;
    inLD = DD; outLD = DD;
  } else {
    int k = z - 24;
    in = Wo + (size_t)k * DD * DD;
    out = Wot + (size_t)k * DD;
    inLD = DD; outLD = BHD;
  }
  const int tx = threadIdx.x, ty = threadIdx.y;
  const int bx = blockIdx.x * 32, by = blockIdx.y * 32;
  for (int kk = 0; kk < 4; ++kk)
    t[ty + 8*kk][tx] = in[(size_t)(by + ty + 8*kk) * inLD + bx + tx];
  __syncthreads();
  for (int kk = 0; kk < 4; ++kk)
    out[(size_t)(bx + ty + 8*kk) * outLD + by + tx] = f2bf(t[tx][ty + 8*kk]);
}

// ---------------- GEMM1: QKV projection + RoPE epilogue ----------------
__global__ __launch_bounds__(256)
void k_qkv(const unsigned short* __restrict__ Abf, const unsigned short* __restrict__ Bt,
           unsigned short* __restrict__ Qr, unsigned short* __restrict__ Kr,
           unsigned short* __restrict__ Vt) {
  __shared__ short As[128*32];
  __shared__ short Bs[128*32];
  const int tid = threadIdx.x;
  const int m0 = blockIdx.x * 128;
  const int n0 = blockIdx.y * 128;
  const int wave = tid >> 6, lane = tid & 63, qd = lane >> 4, c = lane & 15;
  const int wm = (wave >> 1) * 64, wn = (wave & 1) * 64;
  floatx4 acc[4][4] = {};
  const int e0 = tid * 8;
  const int e1 = e0 + 2048;
  for (int k0 = 0; k0 < 512; k0 += 32) {
    __syncthreads();
    async16(&Abf[(size_t)(m0 + (e0 >> 5)) * 512 + k0 + (e0 & 31)], &As[e0]);
    async16(&Abf[(size_t)(m0 + (e1 >> 5)) * 512 + k0 + (e1 & 31)], &As[e1]);
    async16(&Bt [(size_t)(n0 + (e0 >> 5)) * 512 + k0 + (e0 & 31)], &Bs[e0]);
    async16(&Bt [(size_t)(n0 + (e1 >> 5)) * 512 + k0 + (e1 & 31)], &Bs[e1]);
    __syncthreads();
    short8v a[4], bfr[4];
    for (int mt = 0; mt < 4; ++mt) a[mt]   = *(const short8v*)&As[(wm + mt*16 + c)*32 + qd*8];
    for (int nt = 0; nt < 4; ++nt) bfr[nt] = *(const short8v*)&Bs[(wn + nt*16 + c)*32 + qd*8];
    for (int mt = 0; mt < 4; ++mt)
      for (int nt = 0; nt < 4; ++nt)
        acc[mt][nt] = __builtin_amdgcn_mfma_f32_16x16x32_bf16(a[mt], bfr[nt], acc[mt][nt], 0, 0, 0);
  }
  const int tsel = n0 >> 12;
  const int h = (n0 >> 9) & 7;
  const int bat = m0 >> 11;
  const int bh = bat * HH + h;
  const int dloc = (n0 & 511) + wn;
  if (tsel < 2) {
    unsigned short* dst = (tsel == 0) ? Qr : Kr;
    for (int nt = 0; nt < 4; ++nt) {
      const int d = dloc + nt*16 + c;
      const float invf = exp2f(-13.287712379549449f * (1.0f/256.0f) * (float)(d >> 1));
      for (int mt = 0; mt < 4; ++mt) {
        const int mrow = (m0 & 2047) + wm + mt*16 + qd*4;
        for (int r = 0; r < 4; ++r) {
          const int s = mrow + r;
          float v = acc[mt][nt][r];
          float p = __shfl_xor(v, 1, 64);
          float sn, cs;
          __sincosf((float)s * invf, &sn, &cs);
          float res = (d & 1) ? (p * sn + v * cs) : (v * cs - p * sn);
          if (tsel == 0) res *= 0.044194173824159216f;  // 1/sqrt(512) folded into Q
          dst[((size_t)bh * SS + s) * DD + d] = f2bf(res);
        }
      }
    }
  } else {
    for (int nt = 0; nt < 4; ++nt) {
      const int d = dloc + nt*16 + c;
      const size_t vbase = ((size_t)bh * DD + d) * SS;
      for (int mt = 0; mt < 4; ++mt) {
        const int s = (m0 & 2047) + wm + mt*16 + qd*4;
        ushort4 u;
        u.x = f2bf(acc[mt][nt][0]); u.y = f2bf(acc[mt][nt][1]);
        u.z = f2bf(acc[mt][nt][2]); u.w = f2bf(acc[mt][nt][3]);
        *(ushort4*)&Vt[vbase + s] = u;
      }
    }
  }
}

// ---------------- pass A: E = exp(S) panels (bf16, causal triangle) + row sums l_z ----------------
__global__ __launch_bounds__(256)
void k_scores(const unsigned short* __restrict__ Qr, const unsigned short* __restrict__ Kr,
              unsigned short* __restrict__ Eg, float* __restrict__ lsum) {
  __shared__ short UN[17408];   // union: As(4096)+Bs(4096) | ET 128x136
  short* As = UN;
  short* Bs = UN + 4096;
  unsigned short* ET = (unsigned short*)UN;
  const int tid = threadIdx.x;
  const int bh = blockIdx.y;
  const int t = blockIdx.x;
  int zb = 0;
  while (((zb + 1) * (zb + 2)) / 2 <= t) ++zb;
  const int st = t - (zb * (zb + 1)) / 2;
  const int z0 = zb * 128, s0 = st * 128;
  const int wave = tid >> 6, lane = tid & 63, qd = lane >> 4, c = lane & 15;
  const int wm = (wave >> 1) * 64, wn = (wave & 1) * 64;
  const size_t qb = (size_t)bh * SS * DD;
  floatx4 acc[4][4] = {};
  const int e0 = tid * 8, e1 = e0 + 2048;
  for (int k0 = 0; k0 < 512; k0 += 32) {
    __syncthreads();
    async16(&Qr[qb + (size_t)(z0 + (e0 >> 5)) * 512 + k0 + (e0 & 31)], &As[e0]);
    async16(&Qr[qb + (size_t)(z0 + (e1 >> 5)) * 512 + k0 + (e1 & 31)], &As[e1]);
    async16(&Kr[qb + (size_t)(s0 + (e0 >> 5)) * 512 + k0 + (e0 & 31)], &Bs[e0]);
    async16(&Kr[qb + (size_t)(s0 + (e1 >> 5)) * 512 + k0 + (e1 & 31)], &Bs[e1]);
    __syncthreads();
    short8v a[4], bfr[4];
    for (int mt = 0; mt < 4; ++mt) a[mt]   = *(const short8v*)&As[(wm + mt*16 + c)*32 + qd*8];
    for (int nt = 0; nt < 4; ++nt) bfr[nt] = *(const short8v*)&Bs[(wn + nt*16 + c)*32 + qd*8];
    for (int mt = 0; mt < 4; ++mt)
      for (int nt = 0; nt < 4; ++nt)
        acc[mt][nt] = __builtin_amdgcn_mfma_f32_16x16x32_bf16(a[mt], bfr[nt], acc[mt][nt], 0, 0, 0);
  }
  const bool diag = (st == zb);
  for (int mt = 0; mt < 4; ++mt) {
    const int zl = wm + mt*16 + qd*4;
    float rs[4] = {0.f, 0.f, 0.f, 0.f};
    for (int nt = 0; nt < 4; ++nt) {
      const int sl = wn + nt*16 + c;
      for (int r = 0; r < 4; ++r) {
        float ev = __expf(acc[mt][nt][r]);
        if (diag && (sl > zl + r)) ev = 0.f;
        acc[mt][nt][r] = ev;
        rs[r] += ev;
      }
    }
    for (int off = 1; off < 16; off <<= 1)
      for (int r = 0; r < 4; ++r) rs[r] += __shfl_xor(rs[r], off, 64);
    if (c == 0)
      for (int r = 0; r < 4; ++r)
        atomicAdd(&lsum[(size_t)bh * SS + z0 + zl + r], rs[r]);
  }
  __syncthreads();
  for (int mt = 0; mt < 4; ++mt) {
    const int zl = wm + mt*16 + qd*4;
    for (int nt = 0; nt < 4; ++nt) {
      const int sl = wn + nt*16 + c;
      ushort4 u;
      u.x = f2bf(acc[mt][nt][0]); u.y = f2bf(acc[mt][nt][1]);
      u.z = f2bf(acc[mt][nt][2]); u.w = f2bf(acc[mt][nt][3]);
      *(ushort4*)&ET[sl * 136 + zl] = u;
    }
  }
  __syncthreads();
  const size_t tb = ((size_t)bh * NTILE + t) * 16384;
  for (int it = 0; it < 8; ++it) {
    const int e = it * 2048 + tid * 8;
    const int row = e >> 7, col = e & 127;
    *(short8v*)&Eg[tb + row * 128 + col] = *(const short8v*)&ET[row * 136 + col];
  }
}

// ---------------- scale V by 1/l_z in place: Vs[d][z] = V^T[d][z] / l[z] ----------------
__global__ void k_vscale(unsigned short* __restrict__ Vt, const float* __restrict__ lsum) {
  const int idx = (blockIdx.x * 256 + threadIdx.x) * 8;
  const int z = idx & (SS - 1);
  const int bh = idx >> 20;
  short8v v = *(const short8v*)&Vt[idx];
  const float* lp = &lsum[(size_t)bh * SS + z];
  short8v o;
  for (int i = 0; i < 8; ++i)
    o[i] = (short)f2bf(bf2f((unsigned short)v[i]) / lp[i]);
  *(short8v*)&Vt[idx] = o;
}

// ---------------- pass B: out^T(128d x 128s) = sum_z Vs^T(d,z) E^T(s,z) — pure GEMM ----------------
// 128x128 tile, BK=64: 32 MFMA/wave per 32 KB staged (m97 intensity); V traffic halved vs 64-s tiles.
__global__ __launch_bounds__(256)
void k_pv(const unsigned short* __restrict__ Eg, const unsigned short* __restrict__ Vs,
          unsigned short* __restrict__ Ocat) {
  __shared__ short Vl[2][128*32];
  __shared__ short El[2][128*32];
  const int tid = threadIdx.x;
  const int d0 = blockIdx.x * 128;
  const int st = blockIdx.y;          // s-tile of 128 (long blocks st=0 dispatch first per bh)
  const int bh = blockIdx.z;
  const int s0 = st * 128;
  const int bat = bh >> 3, h = bh & 7;
  const int wave = tid >> 6, lane = tid & 63, qd = lane >> 4, c = lane & 15;
  const int wm = (wave >> 1) * 64, wn = (wave & 1) * 64;
  const size_t vbb = (size_t)bh * DD * SS;
  floatx4 acc[4][4] = {};
  const int e = tid * 8;
  for (int zb = st; zb < 16; ++zb) {
    const size_t tb = ((size_t)bh * NTILE + (zb * (zb + 1)) / 2 + st) * 16384;
    for (int half = 0; half < 2; ++half) {
      const int zbase = zb * 128 + half * 64;
      __syncthreads();
      for (int i = 0; i < 4; ++i) {
        const int ee = e + i * 2048;
        const int kc = ee >> 12, row = (ee >> 5) & 127, col = ee & 31;
        async16(&Vs[vbb + (size_t)(d0 + row) * SS + zbase + kc * 32 + col], &Vl[kc][row * 32 + col]);
      }
      for (int i = 0; i < 4; ++i) {
        const int ee = e + i * 2048;
        const int kc = ee >> 12, row = (ee >> 5) & 127, col = ee & 31;
        async16(&Eg[tb + (size_t)row * 128 + half * 64 + kc * 32 + col], &El[kc][row * 32 + col]);
      }
      __syncthreads();
      for (int kc = 0; kc < 2; ++kc) {
        short8v a[4], b[4];
        for (int dt = 0; dt < 4; ++dt) a[dt] = *(const short8v*)&Vl[kc][(wm + dt*16 + c)*32 + qd*8];
        for (int nt = 0; nt < 4; ++nt) b[nt] = *(const short8v*)&El[kc][(wn + nt*16 + c)*32 + qd*8];
        for (int dt = 0; dt < 4; ++dt)
          for (int nt = 0; nt < 4; ++nt)
            acc[dt][nt] = __builtin_amdgcn_mfma_f32_16x16x32_bf16(a[dt], b[nt], acc[dt][nt], 0, 0, 0);
      }
    }
  }
  for (int nt = 0; nt < 4; ++nt) {
    const int sg = s0 + wn + nt*16 + c;
    const size_t ob = ((size_t)(bat * SS + sg)) * BHD + (size_t)h * DD + d0;
    for (int dt = 0; dt < 4; ++dt) {
      const int dloc = wm + dt*16 + qd*4;
      ushort4 u;
      u.x = f2bf(acc[dt][nt][0]); u.y = f2bf(acc[dt][nt][1]);
      u.z = f2bf(acc[dt][nt][2]); u.w = f2bf(acc[dt][nt][3]);
      *(ushort4*)&Ocat[ob + dloc] = u;
    }
  }
}

// ---------------- GEMM4: out += Ocat @ Wo, 128x128 tile, split-K=4, f32 atomics ----------------
__global__ __launch_bounds__(256)
void k_oproj(const unsigned short* __restrict__ Ocat, const unsigned short* __restrict__ Wot,
             float* __restrict__ out) {
  __shared__ short As[128*32];
  __shared__ short Bs[128*32];
  const int tid = threadIdx.x;
  const int m0 = blockIdx.x * 128;
  const int n0 = blockIdx.y * 128;
  const int ks = blockIdx.z * 1024;
  const int wave = tid >> 6, lane = tid & 63, qd = lane >> 4, c = lane & 15;
  const int wm = (wave >> 1) * 64, wn = (wave & 1) * 64;
  floatx4 acc[4][4] = {};
  const int e0 = tid * 8, e1 = e0 + 2048;
  for (int k0 = ks; k0 < ks + 1024; k0 += 32) {
    __syncthreads();
    async16(&Ocat[(size_t)(m0 + (e0 >> 5)) * BHD + k0 + (e0 & 31)], &As[e0]);
    async16(&Ocat[(size_t)(m0 + (e1 >> 5)) * BHD + k0 + (e1 & 31)], &As[e1]);
    async16(&Wot [(size_t)(n0 + (e0 >> 5)) * BHD + k0 + (e0 & 31)], &Bs[e0]);
    async16(&Wot [(size_t)(n0 + (e1 >> 5)) * BHD + k0 + (e1 & 31)], &Bs[e1]);
    __syncthreads();
    short8v a[4], b[4];
    for (int mt = 0; mt < 4; ++mt) a[mt] = *(const short8v*)&As[(wm + mt*16 + c)*32 + qd*8];
    for (int nt = 0; nt < 4; ++nt) b[nt] = *(const short8v*)&Bs[(wn + nt*16 + c)*32 + qd*8];
    for (int mt = 0; mt < 4; ++mt)
      for (int nt = 0; nt < 4; ++nt)
        acc[mt][nt] = __builtin_amdgcn_mfma_f32_16x16x32_bf16(a[mt], b[nt], acc[mt][nt], 0, 0, 0);
  }
  for (int mt = 0; mt < 4; ++mt) {
    const int m = m0 + wm + mt*16 + qd*4;
    for (int nt = 0; nt < 4; ++nt) {
      const int n = n0 + wn + nt*16 + c;
      for (int r = 0; r < 4; ++r)
        atomicAdd(&out[(size_t)(m + r) * DD + n], acc[mt][nt][r]);
    }
  }
}

extern "C" void kernel_launch(void* const* d_in, const int* in_sizes, int n_in,
                              void* d_out, int out_size, void* d_ws, size_t ws_size,
                              hipStream_t stream) {
  const float* q  = (const float*)d_in[0];
  const float* Wq = (const float*)d_in[1];
  const float* Wk = (const float*)d_in[2];
  const float* Wv = (const float*)d_in[3];
  const float* Wo = (const float*)d_in[4];

  // workspace layout with lifetime-based aliasing (peak ~176 MB)
  char* base = (char*)d_ws;
  unsigned short* Eg   = (unsigned short*)base;                       // 71,303,168 B
  unsigned short* qbf  = (unsigned short*)base;                       // overlay (dies after k_qkv)
  unsigned short* Wcat = (unsigned short*)(base + 4194304);           // overlay (dies after k_qkv)
  char* p = base + 71303168;
  unsigned short* Wot  = (unsigned short*)p; p += 4194304;
  unsigned short* Qr   = (unsigned short*)p;
  unsigned short* Ocat = (unsigned short*)p; p += 33554432;           // overlays Qr (dead after k_scores)
  unsigned short* Kr   = (unsigned short*)p; p += 33554432;
  unsigned short* Vt   = (unsigned short*)p; p += 33554432;
  float*          lsum = (float*)p;

  hipMemsetAsync(lsum, 0, (size_t)NBH * SS * 4, stream);
  hipMemsetAsync(d_out, 0, (size_t)NTOK * DD * 4, stream);

  k_convert_q<<<NTOK*DD/1024, 256, 0, stream>>>(q, qbf);
  k_prep_w<<<dim3(16,16,32), dim3(32,8), 0, stream>>>(Wq, Wk, Wv, Wo, Wcat, Wot);
  k_qkv<<<dim3(32,96), 256, 0, stream>>>(qbf, Wcat, Qr, Kr, Vt);
  k_scores<<<dim3(NTILE,16), 256, 0, stream>>>(Qr, Kr, Eg, lsum);
  k_vscale<<<NBH*DD*SS/(256*8), 256, 0, stream>>>(Vt, lsum);
  k_pv<<<dim3(4,16,16), 256, 0, stream>>>(Eg, Vt, Ocat);
  k_oproj<<<dim3(32,4,4), 256, 0, stream>>>(Ocat, Wot, (float*)d_out);
}